// Round 2
// baseline (79.704 us; speedup 1.0000x reference)
//
#include <hip/hip_runtime.h>
#include <math.h>

#define F 128
#define D 256
#define N_CATE 18
#define P 8

// Lane layout: lane = 8*p + j  (p in [0,8) = pref row, j in [0,8) = feature chunk).
// Lane (p,j) loads float4 chunks of pref row p at feature offsets k*32 + j*4 (k=0..3)
// plus matching src/dst chunks, accumulating q_p = src.pref_p and t = src.dst partials.
//
// Math: src.pe_p = w_p*q_p + (1-w_p)*t = s_p*sqrt(F); out = sum_p a_p * s_p * sqrt(F)
//     = sqrt(F) * (sum_p e_p s_p) / (sum_p e_p), e_p = exp(s_p - max_p).
__global__ __launch_bounds__(256) void score_predictor_kernel(
    const float* __restrict__ gnn_emb_src,   // (N_SRC, D)
    const float* __restrict__ gnn_emb_dst,   // (N_DST, D)
    const float* __restrict__ news_pref,     // (N_DST, N_CATE, P, D)
    const float* __restrict__ last_update,   // (N_DST, N_CATE, P)
    const float* __restrict__ time_arr,      // (E,)
    const int*   __restrict__ cate_id,       // (N_SRC,)
    const int*   __restrict__ src_idx,       // (E,)
    const int*   __restrict__ dst_idx,       // (E,)
    float* __restrict__ out,
    int E)
{
    const int wave = (int)((blockIdx.x * blockDim.x + threadIdx.x) >> 6);
    const int lane = (int)(threadIdx.x & 63);
    if (wave >= E) return;
    const int e = wave;
    const int p = lane >> 3;
    const int j = lane & 7;

    // Wave-uniform scalars
    const int s = src_idx[e];
    const int d = dst_idx[e];
    const int c = cate_id[s];
    const float t0 = time_arr[0];

    const float* __restrict__ srow = gnn_emb_src + (size_t)s * D;
    const float* __restrict__ drow = gnn_emb_dst + (size_t)d * D;
    const size_t dc = (size_t)d * N_CATE + (size_t)c;
    const float* __restrict__ prow = news_pref + dc * (size_t)(P * D) + (size_t)p * D;

    // decay weight for this lane's p (uniform within each 8-lane group)
    const float wp = __expf(last_update[dc * P + p] - t0);
    const float omw = 1.0f - wp;

    // partial dots: q_p = src . pref_p, t = src . dst  (16 features per lane)
    float qp = 0.0f, tp = 0.0f;
#pragma unroll
    for (int k = 0; k < 4; ++k) {
        const int off = k * 32 + j * 4;
        const float4 sv = *(const float4*)(srow + off);
        const float4 dv = *(const float4*)(drow + off);
        const float4 pv = *(const float4*)(prow + off);
        qp += sv.x * pv.x + sv.y * pv.y + sv.z * pv.z + sv.w * pv.w;
        tp += sv.x * dv.x + sv.y * dv.y + sv.z * dv.z + sv.w * dv.w;
    }

    // reduce (qp, tp) over j (lane bits 0..2): 6 shfl
#pragma unroll
    for (int m = 1; m <= 4; m <<= 1) {
        qp += __shfl_xor(qp, m, 64);
        tp += __shfl_xor(tp, m, 64);
    }

    // score for this lane's p (replicated across its 8-lane group)
    const float inv_sqrtF = 0.088388347648318447f; // 1/sqrt(128)
    const float sp = (wp * qp + omw * tp) * inv_sqrtF;

    // max over p (lane bits 3..5): 3 shfl
    float mx = sp;
#pragma unroll
    for (int m = 8; m <= 32; m <<= 1) {
        mx = fmaxf(mx, __shfl_xor(mx, m, 64));
    }

    // softmax-weighted average of s_p: 6 shfl
    const float ep = __expf(sp - mx);
    float num = ep * sp;
    float den = ep;
#pragma unroll
    for (int m = 8; m <= 32; m <<= 1) {
        num += __shfl_xor(num, m, 64);
        den += __shfl_xor(den, m, 64);
    }

    if (lane == 0) {
        out[e] = (num / den) * 11.313708498984761f; // sqrt(128)
    }
}

extern "C" void kernel_launch(void* const* d_in, const int* in_sizes, int n_in,
                              void* d_out, int out_size, void* d_ws, size_t ws_size,
                              hipStream_t stream) {
    const float* gnn_emb_src = (const float*)d_in[0];
    const float* gnn_emb_dst = (const float*)d_in[1];
    const float* news_pref   = (const float*)d_in[2];
    const float* last_update = (const float*)d_in[3];
    const float* time_arr    = (const float*)d_in[4];
    const int*   cate_id     = (const int*)d_in[5];
    const int*   src_idx     = (const int*)d_in[6];
    const int*   dst_idx     = (const int*)d_in[7];
    float* out = (float*)d_out;

    const int E = in_sizes[6];           // src_idx length
    const int waves_per_block = 256 / 64;
    const int grid = (E + waves_per_block - 1) / waves_per_block;

    score_predictor_kernel<<<grid, 256, 0, stream>>>(
        gnn_emb_src, gnn_emb_dst, news_pref, last_update, time_arr,
        cate_id, src_idx, dst_idx, out, E);
}